// Round 1
// baseline (539.511 us; speedup 1.0000x reference)
//
#include <hip/hip_runtime.h>
#include <hip/hip_bf16.h>

#define B_ 4
#define H_ 16
#define S_ 2048
#define D_ 64

typedef float  f32x4  __attribute__((ext_vector_type(4)));
typedef short  bf16x8 __attribute__((ext_vector_type(8)));
typedef short  s16x4  __attribute__((ext_vector_type(4)));

__device__ __forceinline__ short f2bf(float f) {
    union { float f; unsigned u; } v; v.f = f;
    unsigned r = v.u + 0x7FFFu + ((v.u >> 16) & 1u);   // RNE
    return (short)(r >> 16);
}

// swizzled 16B-slot index for a [rows][64 bf16] LDS tile (8 slots/row)
__device__ __forceinline__ int swz(int row, int s8) {
    return row * 8 + (s8 ^ (row & 7));
}

__device__ __forceinline__ bf16x8 frag_ld(const short* lds, int row, int s8) {
    return *(const bf16x8*)((const char*)lds + 16 * swz(row, s8));
}

// stage a 64x64 f32 tile (row-major, ld=64) into swizzled bf16 LDS
__device__ __forceinline__ void stage_bf16(short* lds, const float* __restrict__ g, int t) {
#pragma unroll
    for (int i = 0; i < 4; ++i) {
        int f = t + i * 256;              // float4 index 0..1023 (fully coalesced)
        int row = f >> 4;
        int c4  = f & 15;                 // which float4 within the row
        f32x4 val = *(const f32x4*)(g + row * 64 + c4 * 4);
        s16x4 h;
        h.x = f2bf(val.x); h.y = f2bf(val.y); h.z = f2bf(val.z); h.w = f2bf(val.w);
        char* p = (char*)lds + 16 * swz(row, c4 >> 1) + (c4 & 1) * 8;
        *(s16x4*)p = h;
    }
}

// stage a 64x64 f32 V tile TRANSPOSED into swizzled bf16 LDS: Vt[d][k]
__device__ __forceinline__ void stage_vt(short* lds, const float* __restrict__ g, int t) {
#pragma unroll
    for (int p = 0; p < 2; ++p) {
        int k  = p * 32 + (t & 31);
        int d0 = (t >> 5) * 8;
        f32x4 a = *(const f32x4*)(g + k * 64 + d0);
        f32x4 b = *(const f32x4*)(g + k * 64 + d0 + 4);
#pragma unroll
        for (int j = 0; j < 8; ++j) {
            float fv = (j < 4) ? a[j] : b[j - 4];
            int row = d0 + j;                                  // d
            *((short*)((char*)lds + 16 * swz(row, k >> 3)) + (k & 7)) = f2bf(fv);
        }
    }
}

__global__ __launch_bounds__(256)
void attn_kernel(const float* __restrict__ Q, const float* __restrict__ K,
                 const float* __restrict__ V, float* __restrict__ Out) {
    const int t    = threadIdx.x;
    const int lane = t & 63;
    const int w    = t >> 6;        // wave 0..3
    const int l15  = lane & 15;
    const int l4   = lane >> 4;     // 0..3

    const int bid = blockIdx.x;
    const int qb  = bid & 31;       // q-tile index (64 rows each)
    const int bh  = bid >> 5;
    const int q0  = qb * 64;

    const float* Qg = Q + ((size_t)bh * S_ + q0) * D_;
    const float* Kg = K + (size_t)bh * S_ * D_;
    const float* Vg = V + (size_t)bh * S_ * D_;
    float* Og = Out + ((size_t)bh * S_ + q0) * D_;
    float* Wg = Out + (size_t)B_ * H_ * S_ * D_ + ((size_t)bh * S_ + q0) * (size_t)S_;

    __shared__ short lq[4096];
    __shared__ short lk[4096];
    __shared__ short lv[4096];
    __shared__ short lp[4][1024];

    // -------- zero-fill the fully-masked upper-triangle weight tiles --------
    {
        int c0 = (qb + 1) * 64;
        if (c0 < S_) {
            f32x4 z = {0.f, 0.f, 0.f, 0.f};
            for (int row = 0; row < 64; ++row) {
                float* p = Wg + (size_t)row * S_;
                for (int c = c0 + 4 * t; c < S_; c += 1024)
                    *(f32x4*)(p + c) = z;
            }
        }
    }

    // -------- stage Q tile, build per-wave Q A-fragments (persist in regs) ----
    stage_bf16(lq, Qg, t);
    __syncthreads();
    const int qrow = 16 * w + l15;
    bf16x8 qa0 = frag_ld(lq, qrow, 0 + l4);    // d-chunk 0..31
    bf16x8 qa1 = frag_ld(lq, qrow, 4 + l4);    // d-chunk 32..63

    // ---------------- sweep 1: row sums l (fixed max = 20) -------------------
    float lsum[4] = {0.f, 0.f, 0.f, 0.f};
    for (int kt = 0; kt <= qb; ++kt) {
        __syncthreads();
        stage_bf16(lk, Kg + (size_t)kt * 64 * 64, t);
        __syncthreads();
#pragma unroll
        for (int kc = 0; kc < 4; ++kc) {
            const int krow = 16 * kc + l15;
            bf16x8 kb0 = frag_ld(lk, krow, 0 + l4);
            bf16x8 kb1 = frag_ld(lk, krow, 4 + l4);
            f32x4 acc = {0.f, 0.f, 0.f, 0.f};
            acc = __builtin_amdgcn_mfma_f32_16x16x32_bf16(qa0, kb0, acc, 0, 0, 0);
            acc = __builtin_amdgcn_mfma_f32_16x16x32_bf16(qa1, kb1, acc, 0, 0, 0);
            const int kg = kt * 64 + 16 * kc + l15;
#pragma unroll
            for (int r = 0; r < 4; ++r) {
                const int qg = q0 + 16 * w + 4 * l4 + r;
                if (kg <= qg)
                    lsum[r] += __expf(fmaf(acc[r], 0.125f, -20.0f));
            }
        }
    }
    float linv[4];
#pragma unroll
    for (int r = 0; r < 4; ++r) {
        float v = lsum[r];
        v += __shfl_xor(v, 1);
        v += __shfl_xor(v, 2);
        v += __shfl_xor(v, 4);
        v += __shfl_xor(v, 8);
        linv[r] = 1.0f / v;
    }

    // ------------- sweep 2: weights write + PV accumulation -------------------
    f32x4 oacc[4];
#pragma unroll
    for (int dt = 0; dt < 4; ++dt) oacc[dt] = (f32x4){0.f, 0.f, 0.f, 0.f};

    short* myP = lp[w];
    for (int kt = 0; kt <= qb; ++kt) {
        __syncthreads();
        stage_bf16(lk, Kg + (size_t)kt * 64 * 64, t);
        stage_vt (lv, Vg + (size_t)kt * 64 * 64, t);
        __syncthreads();

#pragma unroll
        for (int kc = 0; kc < 4; ++kc) {
            const int krow = 16 * kc + l15;
            bf16x8 kb0 = frag_ld(lk, krow, 0 + l4);
            bf16x8 kb1 = frag_ld(lk, krow, 4 + l4);
            f32x4 acc = {0.f, 0.f, 0.f, 0.f};
            acc = __builtin_amdgcn_mfma_f32_16x16x32_bf16(qa0, kb0, acc, 0, 0, 0);
            acc = __builtin_amdgcn_mfma_f32_16x16x32_bf16(qa1, kb1, acc, 0, 0, 0);
            const int kg = kt * 64 + 16 * kc + l15;
#pragma unroll
            for (int r = 0; r < 4; ++r) {
                const int qg = q0 + 16 * w + 4 * l4 + r;
                float wv = 0.0f;
                if (kg <= qg)
                    wv = __expf(fmaf(acc[r], 0.125f, -20.0f)) * linv[r];
                // global weights store (f32)
                Wg[(size_t)(16 * w + 4 * l4 + r) * S_ + (size_t)kt * 64 + 16 * kc + l15] = wv;
                // P -> LDS (bf16, swizzled) for the PV MFMA A-fragment
                const int prow = 4 * l4 + r;
                const int pcol = 16 * kc + l15;
                *((short*)((char*)myP + 16 * swz(prow, pcol >> 3)) + (pcol & 7)) = f2bf(wv);
            }
        }

        // PV: O[16q x 64d] += P(16x64) * V(64x64); per-wave private P, shared Vt
#pragma unroll
        for (int kchunk = 0; kchunk < 2; ++kchunk) {
            bf16x8 pa = frag_ld(myP, l15, kchunk * 4 + l4);
#pragma unroll
            for (int dt = 0; dt < 4; ++dt) {
                bf16x8 vb = frag_ld(lv, 16 * dt + l15, kchunk * 4 + l4);
                oacc[dt] = __builtin_amdgcn_mfma_f32_16x16x32_bf16(pa, vb, oacc[dt], 0, 0, 0);
            }
        }
    }

    // -------- write O --------
#pragma unroll
    for (int dt = 0; dt < 4; ++dt)
#pragma unroll
        for (int r = 0; r < 4; ++r)
            Og[(size_t)(16 * w + 4 * l4 + r) * D_ + 16 * dt + l15] = oacc[dt][r];
}

extern "C" void kernel_launch(void* const* d_in, const int* in_sizes, int n_in,
                              void* d_out, int out_size, void* d_ws, size_t ws_size,
                              hipStream_t stream) {
    const float* q = (const float*)d_in[0];
    const float* k = (const float*)d_in[1];
    const float* v = (const float*)d_in[2];
    float* out = (float*)d_out;
    attn_kernel<<<dim3(B_ * H_ * (S_ / 64)), dim3(256), 0, stream>>>(q, k, v, out);
}

// Round 2
// 432.518 us; speedup vs baseline: 1.2474x; 1.2474x over previous
//
#include <hip/hip_runtime.h>
#include <hip/hip_bf16.h>

#define B_ 4
#define H_ 16
#define S_ 2048
#define D_ 64
#define QBLK 128
#define NQB 16        // S_/QBLK
#define THREADS 512

typedef float  f32x4  __attribute__((ext_vector_type(4)));
typedef short  bf16x8 __attribute__((ext_vector_type(8)));
typedef short  s16x4  __attribute__((ext_vector_type(4)));

__device__ __forceinline__ short f2bf(float f) {
    union { float f; unsigned u; } v; v.f = f;
    unsigned r = v.u + 0x7FFFu + ((v.u >> 16) & 1u);   // RNE
    return (short)(r >> 16);
}

// swizzled 16B-slot index for a [rows][64 bf16] LDS tile (8 slots/row)
// xor term uses row bits [2:0]^[5:3] so both 16-row-stride frag reads and
// 4-row-stride transpose writes spread across banks (2-way max = free)
__device__ __forceinline__ int swz(int row, int s8) {
    return row * 8 + (s8 ^ ((row & 7) ^ ((row >> 3) & 7)));
}

__device__ __forceinline__ bf16x8 frag_ld(const short* lds, int row, int s8) {
    return *(const bf16x8*)((const char*)lds + 16 * swz(row, s8));
}

// ---- K-tile (64x64 f32) reg staging: 2 f32x4 per thread (512 threads) ----
__device__ __forceinline__ void kload(f32x4 (&r)[2], const float* __restrict__ g, int t) {
    r[0] = *(const f32x4*)(g + 4 * t);
    r[1] = *(const f32x4*)(g + 4 * (t + THREADS));
}
__device__ __forceinline__ void kwrite(short* lds, const f32x4 (&r)[2], int t) {
#pragma unroll
    for (int i = 0; i < 2; ++i) {
        int f = t + i * THREADS;
        int row = f >> 4, c4 = f & 15;
        s16x4 h;
        h.x = f2bf(r[i].x); h.y = f2bf(r[i].y); h.z = f2bf(r[i].z); h.w = f2bf(r[i].w);
        *(s16x4*)((char*)lds + 16 * swz(row, c4 >> 1) + (c4 & 1) * 8) = h;
    }
}
// ---- V-tile (64x64) reg staging for TRANSPOSED store: rows k0,k0+1, cols d0..d0+3
__device__ __forceinline__ void vload(f32x4 (&r)[2], const float* __restrict__ g, int t) {
    int k0 = (t >> 4) * 2, d0 = (t & 15) * 4;
    r[0] = *(const f32x4*)(g + k0 * 64 + d0);
    r[1] = *(const f32x4*)(g + (k0 + 1) * 64 + d0);
}
__device__ __forceinline__ void vtwrite(short* lds, const f32x4 (&r)[2], int t) {
    int k0 = (t >> 4) * 2, d0 = (t & 15) * 4;
#pragma unroll
    for (int j = 0; j < 4; ++j) {
        unsigned lo = (unsigned short)f2bf(r[0][j]);
        unsigned hi = (unsigned short)f2bf(r[1][j]);
        int row = d0 + j;                               // d -> Vt row
        *(unsigned*)((char*)lds + 16 * swz(row, k0 >> 3) + (k0 & 7) * 2) = lo | (hi << 16);
    }
}

__global__ __launch_bounds__(THREADS)
void attn_kernel(const float* __restrict__ Q, const float* __restrict__ K,
                 const float* __restrict__ V, float* __restrict__ Out) {
    const int t    = threadIdx.x;
    const int lane = t & 63;
    const int w    = t >> 6;        // wave 0..7
    const int l15  = lane & 15;
    const int l4   = lane >> 4;     // 0..3

    // XCD-chunked swizzle (nwg=1024, bijective) + heavy-first within each head
    const int bid     = blockIdx.x;
    const int logical = (bid & 7) * 128 + (bid >> 3);
    const int qbi     = (NQB - 1) - (logical & (NQB - 1));
    const int bh      = logical >> 4;
    const int q0      = qbi * QBLK;

    const float* Qg = Q + ((size_t)bh * S_ + q0) * D_;
    const float* Kg = K + (size_t)bh * S_ * D_;
    const float* Vg = V + (size_t)bh * S_ * D_;
    float* Og = Out + ((size_t)bh * S_ + q0) * D_;
    float* Wg = Out + (size_t)B_ * H_ * S_ * D_ + ((size_t)bh * S_ + q0) * (size_t)S_;

    __shared__ char pool[49152];
    short* lq  = (short*)pool;               // 16KB (Q tile; dead after frag read)
    short* lvb = (short*)pool;               // sweep2: Vt double-buffer 2x8KB (overlays lq)
    short* lkb = (short*)(pool + 16384);     // K double-buffer 2x8KB
    short* lp  = (short*)(pool + 32768) + w * 1024;  // per-wave P tile 2KB

    // -------- zero-fill masked weight region: per row qg, cols >= (qg&~15)+16 ----
    {
        f32x4 z = {0.f, 0.f, 0.f, 0.f};
        for (int row = 0; row < QBLK; ++row) {
            int c0 = q0 + (row & ~15) + 16;
            float* p = Wg + (size_t)row * S_;
            for (int c = c0 + 4 * t; c < S_; c += 4 * THREADS)
                *(f32x4*)(p + c) = z;
        }
    }

    // -------- stage Q tile (128x64), read per-wave A-fragments --------
#pragma unroll
    for (int i = 0; i < 4; ++i) {
        int f = t + i * THREADS;
        f32x4 val = *(const f32x4*)(Qg + 4 * f);
        int row = f >> 4, c4 = f & 15;
        s16x4 h;
        h.x = f2bf(val.x); h.y = f2bf(val.y); h.z = f2bf(val.z); h.w = f2bf(val.w);
        *(s16x4*)((char*)lq + 16 * swz(row, c4 >> 1) + (c4 & 1) * 8) = h;
    }
    __syncthreads();
    const int qrow = 16 * w + l15;
    bf16x8 qa0 = frag_ld(lq, qrow, 0 + l4);
    bf16x8 qa1 = frag_ld(lq, qrow, 4 + l4);

    const int ktmax = (q0 + QBLK - 1) >> 6;        // inclusive
    const int qgmax = q0 + 16 * w + 15;            // this wave's max q row

    // ---------------- sweep 1: row sums (fixed max = 20), dbuf + prefetch ------
    f32x4 kreg[2];
    kload(kreg, Kg, t);
    __syncthreads();               // all waves done reading lq before... (lkb disjoint, but cheap)
    kwrite(lkb, kreg, t);
    __syncthreads();

    float lsum[4] = {0.f, 0.f, 0.f, 0.f};
    for (int kt = 0; kt <= ktmax; ++kt) {
        if (kt < ktmax) kload(kreg, Kg + (size_t)(kt + 1) * 4096, t);
        const short* lk = lkb + (kt & 1) * 4096;
        if (kt * 64 <= qgmax) {
#pragma unroll
            for (int kc = 0; kc < 4; ++kc) {
                int kgb = kt * 64 + 16 * kc;
                if (kgb > qgmax) break;             // wave-uniform
                bf16x8 kb0 = frag_ld(lk, 16 * kc + l15, 0 + l4);
                bf16x8 kb1 = frag_ld(lk, 16 * kc + l15, 4 + l4);
                f32x4 acc = {0.f, 0.f, 0.f, 0.f};
                acc = __builtin_amdgcn_mfma_f32_16x16x32_bf16(qa0, kb0, acc, 0, 0, 0);
                acc = __builtin_amdgcn_mfma_f32_16x16x32_bf16(qa1, kb1, acc, 0, 0, 0);
                int kg = kgb + l15;
#pragma unroll
                for (int r = 0; r < 4; ++r) {
                    int qg = q0 + 16 * w + 4 * l4 + r;
                    if (kg <= qg) lsum[r] += __expf(fmaf(acc[r], 0.125f, -20.0f));
                }
            }
        }
        __syncthreads();
        if (kt < ktmax) { kwrite(lkb + ((kt + 1) & 1) * 4096, kreg, t); __syncthreads(); }
    }
    float linv[4];
#pragma unroll
    for (int r = 0; r < 4; ++r) {
        float v = lsum[r];
        v += __shfl_xor(v, 1);
        v += __shfl_xor(v, 2);
        v += __shfl_xor(v, 4);
        v += __shfl_xor(v, 8);
        linv[r] = 1.0f / v;
    }

    // ------------- sweep 2: weights write + PV, dbuf + prefetch ----------------
    f32x4 oacc[4];
#pragma unroll
    for (int dt = 0; dt < 4; ++dt) oacc[dt] = (f32x4){0.f, 0.f, 0.f, 0.f};

    f32x4 vreg[2];
    kload(kreg, Kg, t);
    vload(vreg, Vg, t);
    // all waves passed sweep1's final barrier -> lkb reads done; lq (lvb) long dead
    kwrite(lkb, kreg, t);
    vtwrite(lvb, vreg, t);
    __syncthreads();

    for (int kt = 0; kt <= ktmax; ++kt) {
        if (kt < ktmax) {
            kload(kreg, Kg + (size_t)(kt + 1) * 4096, t);
            vload(vreg, Vg + (size_t)(kt + 1) * 4096, t);
        }
        const short* lk = lkb + (kt & 1) * 4096;
        const short* lv = lvb + (kt & 1) * 4096;

        if (kt * 64 <= qgmax) {                    // wave-uniform: tile has live cols
#pragma unroll
            for (int kc = 0; kc < 4; ++kc) {
                int kgb = kt * 64 + 16 * kc;
                bool live = (kgb <= qgmax);        // wave-uniform
                f32x4 acc = {0.f, 0.f, 0.f, 0.f};
                if (live) {
                    bf16x8 kb0 = frag_ld(lk, 16 * kc + l15, 0 + l4);
                    bf16x8 kb1 = frag_ld(lk, 16 * kc + l15, 4 + l4);
                    acc = __builtin_amdgcn_mfma_f32_16x16x32_bf16(qa0, kb0, acc, 0, 0, 0);
                    acc = __builtin_amdgcn_mfma_f32_16x16x32_bf16(qa1, kb1, acc, 0, 0, 0);
                }
                int kg = kgb + l15;
#pragma unroll
                for (int r = 0; r < 4; ++r) {
                    int qg = q0 + 16 * w + 4 * l4 + r;
                    float wv = 0.0f;
                    if (live && kg <= qg)
                        wv = __expf(fmaf(acc[r], 0.125f, -20.0f)) * linv[r];
                    if (live)
                        Wg[(size_t)(16 * w + 4 * l4 + r) * S_ + kgb + l15] = wv;
                    // P -> per-wave LDS (zeros for masked chunks keep lp fresh)
                    int prow = 4 * l4 + r, pcol = 16 * kc + l15;
                    *((short*)((char*)lp + 16 * swz(prow, pcol >> 3)) + (pcol & 7)) = f2bf(wv);
                }
            }
            // PV: O[16q x 64d] += P(16x64) * V(64x64)^T-staged
#pragma unroll
            for (int kchunk = 0; kchunk < 2; ++kchunk) {
                bf16x8 pa = frag_ld(lp, l15, kchunk * 4 + l4);
#pragma unroll
                for (int dt = 0; dt < 4; ++dt) {
                    bf16x8 vb = frag_ld(lv, 16 * dt + l15, kchunk * 4 + l4);
                    oacc[dt] = __builtin_amdgcn_mfma_f32_16x16x32_bf16(pa, vb, oacc[dt], 0, 0, 0);
                }
            }
        }
        __syncthreads();
        if (kt < ktmax) {
            kwrite(lkb + ((kt + 1) & 1) * 4096, kreg, t);
            vtwrite(lvb + ((kt + 1) & 1) * 4096, vreg, t);
            __syncthreads();
        }
    }

    // -------- write O --------
#pragma unroll
    for (int dt = 0; dt < 4; ++dt)
#pragma unroll
        for (int r = 0; r < 4; ++r)
            Og[(size_t)(16 * w + 4 * l4 + r) * D_ + 16 * dt + l15] = oacc[dt][r];
}

extern "C" void kernel_launch(void* const* d_in, const int* in_sizes, int n_in,
                              void* d_out, int out_size, void* d_ws, size_t ws_size,
                              hipStream_t stream) {
    const float* q = (const float*)d_in[0];
    const float* k = (const float*)d_in[1];
    const float* v = (const float*)d_in[2];
    float* out = (float*)d_out;
    attn_kernel<<<dim3(B_ * H_ * NQB), dim3(THREADS), 0, stream>>>(q, k, v, out);
}

// Round 3
// 380.749 us; speedup vs baseline: 1.4170x; 1.1360x over previous
//
#include <hip/hip_runtime.h>
#include <hip/hip_bf16.h>

#define B_ 4
#define H_ 16
#define S_ 2048
#define D_ 64
#define QBLK 128
#define NQB 16        // S_/QBLK
#define THREADS 512

typedef float  f32x4  __attribute__((ext_vector_type(4)));
typedef short  bf16x8 __attribute__((ext_vector_type(8)));
typedef short  s16x4  __attribute__((ext_vector_type(4)));

#define LOG2E_O8  0.18033688011112042f   // log2(e)/8
#define M20LOG2E -28.853900817779268f    // -20*log2(e)

__device__ __forceinline__ short f2bf(float f) {
    union { float f; unsigned u; } v; v.f = f;
    unsigned r = v.u + 0x7FFFu + ((v.u >> 16) & 1u);   // RNE
    return (short)(r >> 16);
}

// swizzled 16B-slot index for a [rows][64 bf16] LDS tile (8 slots/row)
__device__ __forceinline__ int swz(int row, int s8) {
    return row * 8 + (s8 ^ ((row & 7) ^ ((row >> 3) & 7)));
}

__device__ __forceinline__ bf16x8 frag_ld(const short* lds, int row, int s8) {
    return *(const bf16x8*)((const char*)lds + 16 * swz(row, s8));
}

// ---- K-tile (64x64 f32) reg staging: 2 f32x4 per thread (512 threads) ----
__device__ __forceinline__ void kload(f32x4 (&r)[2], const float* __restrict__ g, int t) {
    r[0] = *(const f32x4*)(g + 4 * t);
    r[1] = *(const f32x4*)(g + 4 * (t + THREADS));
}
__device__ __forceinline__ void kwrite(short* lds, const f32x4 (&r)[2], int t) {
#pragma unroll
    for (int i = 0; i < 2; ++i) {
        int f = t + i * THREADS;
        int row = f >> 4, c4 = f & 15;
        s16x4 h;
        h.x = f2bf(r[i].x); h.y = f2bf(r[i].y); h.z = f2bf(r[i].z); h.w = f2bf(r[i].w);
        *(s16x4*)((char*)lds + 16 * swz(row, c4 >> 1) + (c4 & 1) * 8) = h;
    }
}
// ---- V-tile (64x64) reg staging for TRANSPOSED store ----
__device__ __forceinline__ void vload(f32x4 (&r)[2], const float* __restrict__ g, int t) {
    int k0 = (t >> 4) * 2, d0 = (t & 15) * 4;
    r[0] = *(const f32x4*)(g + k0 * 64 + d0);
    r[1] = *(const f32x4*)(g + (k0 + 1) * 64 + d0);
}
__device__ __forceinline__ void vtwrite(short* lds, const f32x4 (&r)[2], int t) {
    int k0 = (t >> 4) * 2, d0 = (t & 15) * 4;
#pragma unroll
    for (int j = 0; j < 4; ++j) {
        unsigned lo = (unsigned short)f2bf(r[0][j]);
        unsigned hi = (unsigned short)f2bf(r[1][j]);
        int row = d0 + j;                               // d -> Vt row
        *(unsigned*)((char*)lds + 16 * swz(row, k0 >> 3) + (k0 & 7) * 2) = lo | (hi << 16);
    }
}

__global__ __launch_bounds__(THREADS)
void attn_kernel(const float* __restrict__ Q, const float* __restrict__ K,
                 const float* __restrict__ V, float* __restrict__ Out) {
    const int t    = threadIdx.x;
    const int lane = t & 63;
    const int w    = t >> 6;        // wave 0..7
    const int l15  = lane & 15;
    const int l4   = lane >> 4;     // 0..3

    // XCD-chunked swizzle (nwg=1024, bijective) + heavy-first within each head
    const int bid     = blockIdx.x;
    const int logical = (bid & 7) * 128 + (bid >> 3);
    const int qbi     = (NQB - 1) - (logical & (NQB - 1));
    const int bh      = logical >> 4;
    const int q0      = qbi * QBLK;

    const float* Qg = Q + ((size_t)bh * S_ + q0) * D_;
    const float* Kg = K + (size_t)bh * S_ * D_;
    const float* Vg = V + (size_t)bh * S_ * D_;
    float* Og = Out + ((size_t)bh * S_ + q0) * D_;
    float* Wg = Out + (size_t)B_ * H_ * S_ * D_ + ((size_t)bh * S_ + q0) * (size_t)S_;

    __shared__ char pool[49152];
    short* lq  = (short*)pool;               // 16KB (Q tile; dead after frag read)
    short* lvb = (short*)pool;               // sweep2: Vt double-buffer 2x8KB (overlays lq)
    short* lkb = (short*)(pool + 16384);     // K double-buffer 2x8KB
    short* lp  = (short*)(pool + 32768) + w * 1024;  // per-wave P tile 2KB

    // -------- zero-fill masked weight region: per row qg, cols >= (qg&~15)+16 ----
    {
        f32x4 z = {0.f, 0.f, 0.f, 0.f};
        for (int row = 0; row < QBLK; ++row) {
            int c0 = q0 + (row & ~15) + 16;
            float* p = Wg + (size_t)row * S_;
            for (int c = c0 + 4 * t; c < S_; c += 4 * THREADS)
                *(f32x4*)(p + c) = z;
        }
    }

    // -------- stage Q tile (128x64), read per-wave fragments --------
#pragma unroll
    for (int i = 0; i < 4; ++i) {
        int f = t + i * THREADS;
        f32x4 val = *(const f32x4*)(Qg + 4 * f);
        int row = f >> 4, c4 = f & 15;
        s16x4 h;
        h.x = f2bf(val.x); h.y = f2bf(val.y); h.z = f2bf(val.z); h.w = f2bf(val.w);
        *(s16x4*)((char*)lq + 16 * swz(row, c4 >> 1) + (c4 & 1) * 8) = h;
    }
    __syncthreads();
    const int qrow = 16 * w + l15;
    bf16x8 qa0 = frag_ld(lq, qrow, 0 + l4);
    bf16x8 qa1 = frag_ld(lq, qrow, 4 + l4);

    const int ktmax = (q0 + QBLK - 1) >> 6;        // inclusive
    const int qgmax = q0 + 16 * w + 15;            // this wave's max q row
    const int qg    = q0 + 16 * w + l15;           // this lane's q row (S^T layout)

    // ---------------- sweep 1: row sums (fixed max = 20), dbuf + prefetch ------
    // swapped QK^T: mfma(K,Q) -> lane holds S[q=l15][k=kgb+4*l4+r]
    f32x4 kreg[2];
    kload(kreg, Kg, t);
    __syncthreads();               // lq reads complete everywhere
    kwrite(lkb, kreg, t);
    __syncthreads();

    float lsum = 0.0f;
    for (int kt = 0; kt <= ktmax; ++kt) {
        if (kt < ktmax) kload(kreg, Kg + (size_t)(kt + 1) * 4096, t);
        const short* lk = lkb + (kt & 1) * 4096;
#pragma unroll
        for (int kc = 0; kc < 4; ++kc) {
            int kgb = kt * 64 + 16 * kc;
            if (kgb > qgmax) break;             // wave-uniform
            bf16x8 kb0 = frag_ld(lk, 16 * kc + l15, 0 + l4);
            bf16x8 kb1 = frag_ld(lk, 16 * kc + l15, 4 + l4);
            f32x4 acc = {0.f, 0.f, 0.f, 0.f};
            acc = __builtin_amdgcn_mfma_f32_16x16x32_bf16(kb0, qa0, acc, 0, 0, 0);
            acc = __builtin_amdgcn_mfma_f32_16x16x32_bf16(kb1, qa1, acc, 0, 0, 0);
#pragma unroll
            for (int r = 0; r < 4; ++r) {
                int kg = kgb + 4 * l4 + r;
                if (kg <= qg) lsum += exp2f(fmaf(acc[r], LOG2E_O8, M20LOG2E));
            }
        }
        __syncthreads();
        if (kt < ktmax) { kwrite(lkb + ((kt + 1) & 1) * 4096, kreg, t); __syncthreads(); }
    }
    // combine the 4 k-subsets (lane bits 4,5) -> per-lane row sum for q = l15
    lsum += __shfl_xor(lsum, 16);
    lsum += __shfl_xor(lsum, 32);
    const float linv = 1.0f / lsum;

    // ------------- sweep 2: weights write + PV, dbuf + prefetch ----------------
    f32x4 oacc[4];
#pragma unroll
    for (int dt = 0; dt < 4; ++dt) oacc[dt] = (f32x4){0.f, 0.f, 0.f, 0.f};

    f32x4 vreg[2];
    kload(kreg, Kg, t);
    vload(vreg, Vg, t);
    kwrite(lkb, kreg, t);          // all waves passed sweep1's final barrier
    vtwrite(lvb, vreg, t);
    __syncthreads();

    for (int kt = 0; kt <= ktmax; ++kt) {
        if (kt < ktmax) {
            kload(kreg, Kg + (size_t)(kt + 1) * 4096, t);
            vload(vreg, Vg + (size_t)(kt + 1) * 4096, t);
        }
        const short* lk = lkb + (kt & 1) * 4096;
        const short* lv = lvb + (kt & 1) * 4096;

        if (kt * 64 <= qgmax) {                    // wave-uniform: tile has live cols
#pragma unroll
            for (int kc = 0; kc < 4; ++kc) {
                int kgb = kt * 64 + 16 * kc;
                bool live = (kgb <= qgmax);        // wave-uniform
                f32x4 wv;
                if (live) {
                    bf16x8 kb0 = frag_ld(lk, 16 * kc + l15, 0 + l4);
                    bf16x8 kb1 = frag_ld(lk, 16 * kc + l15, 4 + l4);
                    f32x4 acc = {0.f, 0.f, 0.f, 0.f};
                    acc = __builtin_amdgcn_mfma_f32_16x16x32_bf16(kb0, qa0, acc, 0, 0, 0);
                    acc = __builtin_amdgcn_mfma_f32_16x16x32_bf16(kb1, qa1, acc, 0, 0, 0);
#pragma unroll
                    for (int r = 0; r < 4; ++r) {
                        int kg = kgb + 4 * l4 + r;
                        wv[r] = (kg <= qg) ? exp2f(fmaf(acc[r], LOG2E_O8, M20LOG2E)) * linv : 0.0f;
                    }
                    // vectorized weights store: row q=l15, 4 consecutive cols
                    *(f32x4*)(Wg + (size_t)(16 * w + l15) * S_ + kgb + 4 * l4) = wv;
                } else {
                    wv = (f32x4){0.f, 0.f, 0.f, 0.f};
                }
                // P -> per-wave LDS: 4 bf16 packed, row q=l15, cols 16kc+4l4..+3
                unsigned lo = (unsigned short)f2bf(wv[0]) | ((unsigned)(unsigned short)f2bf(wv[1]) << 16);
                unsigned hi = (unsigned short)f2bf(wv[2]) | ((unsigned)(unsigned short)f2bf(wv[3]) << 16);
                unsigned long long pk = (unsigned long long)lo | ((unsigned long long)hi << 32);
                int s8 = 2 * kc + (l4 >> 1);
                *(unsigned long long*)((char*)lp + 16 * swz(l15, s8) + (l4 & 1) * 8) = pk;
            }
            // PV: O[16q x 64d] += P(16x64) * V(64x64)^T-staged
#pragma unroll
            for (int kchunk = 0; kchunk < 2; ++kchunk) {
                bf16x8 pa = frag_ld(lp, l15, kchunk * 4 + l4);
#pragma unroll
                for (int dt = 0; dt < 4; ++dt) {
                    bf16x8 vb = frag_ld(lv, 16 * dt + l15, kchunk * 4 + l4);
                    oacc[dt] = __builtin_amdgcn_mfma_f32_16x16x32_bf16(pa, vb, oacc[dt], 0, 0, 0);
                }
            }
        }
        __syncthreads();
        if (kt < ktmax) {
            kwrite(lkb + ((kt + 1) & 1) * 4096, kreg, t);
            vtwrite(lvb + ((kt + 1) & 1) * 4096, vreg, t);
            __syncthreads();
        }
    }

    // -------- write O --------
#pragma unroll
    for (int dt = 0; dt < 4; ++dt)
#pragma unroll
        for (int r = 0; r < 4; ++r)
            Og[(size_t)(16 * w + 4 * l4 + r) * D_ + 16 * dt + l15] = oacc[dt][r];
}

extern "C" void kernel_launch(void* const* d_in, const int* in_sizes, int n_in,
                              void* d_out, int out_size, void* d_ws, size_t ws_size,
                              hipStream_t stream) {
    const float* q = (const float*)d_in[0];
    const float* k = (const float*)d_in[1];
    const float* v = (const float*)d_in[2];
    float* out = (float*)d_out;
    attn_kernel<<<dim3(B_ * H_ * NQB), dim3(THREADS), 0, stream>>>(q, k, v, out);
}